// Round 15
// baseline (325.918 us; speedup 1.0000x reference)
//
#include <hip/hip_runtime.h>
#include <hip/hip_bf16.h>

#define D 128
#define NGRAPH 64
#define POOLBLK 256     // blocks in k_pool_edges
#define PBCHUNK 2048    // edges per block in k_part
#define WINSZ 128       // nodes per dst-window
#define WINSLOTS 8192   // edge slots per window (mean ~4092, big headroom)
#define NBMAX 800       // max windows (782 for n=100000)
#define XP 136          // padded LDS row (bf16) -> 2-way bank aliasing only

typedef __attribute__((ext_vector_type(4))) float f32x4;
typedef __attribute__((ext_vector_type(8))) short bf16x8;
typedef __attribute__((ext_vector_type(2))) int int2v;
typedef __attribute__((ext_vector_type(4))) int int4v;

__device__ __forceinline__ unsigned short f2bf(float f) {
    union { float f; unsigned int i; } u; u.f = f;
    unsigned int r = u.i + 0x7fffu + ((u.i >> 16) & 1u);   // round-to-nearest-even
    return (unsigned short)(r >> 16);
}
__device__ __forceinline__ float2 bf2_to_f2(unsigned int u) {
    union { unsigned int i; float f; } a, b;
    a.i = u << 16;            // low ushort  = element 0
    b.i = u & 0xffff0000u;    // high ushort = element 1
    return make_float2(a.f, b.f);
}

// ---------------- prep: Weff = W2@Wc, beff, and zero cursor/tsum/cnt -----

__global__ __launch_bounds__(256) void k_prep(const float* __restrict__ W2,
                                              const float* __restrict__ Wc,
                                              const float* __restrict__ b2,
                                              const float* __restrict__ bc,
                                              float* __restrict__ Weff,
                                              float* __restrict__ beff,
                                              int* __restrict__ zero_region,
                                              int zero_words) {
    int t = threadIdx.x;
    int i = t >> 1, c = t & 1;
    float acc = 0.f;
    for (int k = 0; k < D; ++k) acc += W2[i * D + k] * Wc[k * 2 + c];
    Weff[i * 2 + c] = acc;
    if (i == 0) {
        float s = 0.f;
        for (int k = 0; k < D; ++k) s += b2[k] * Wc[k * 2 + c];
        beff[c] = s + bc[c];
    }
    for (int j = t; j < zero_words; j += 256) zero_region[j] = 0;
}

// ---------------- CSR build: windowed counting sort ----------------------
// pack = src (17b) | (dst & 127) << 17 ; bin = dst >> 7

__global__ __launch_bounds__(256) void k_part(const int* __restrict__ src,
                                              const int* __restrict__ dst,
                                              int* __restrict__ cursor,
                                              unsigned* __restrict__ ebuf,
                                              int E, int nb) {
    __shared__ unsigned spack[PBCHUNK];
    __shared__ unsigned short sbin[PBCHUNK];
    __shared__ unsigned short slrank[PBCHUNK];
    __shared__ int hist[NBMAX];
    __shared__ int base[NBMAX];
    int tid = threadIdx.x;
    for (int i = tid; i < nb; i += 256) hist[i] = 0;
    __syncthreads();
    int b0 = blockIdx.x * PBCHUNK;
    int cnt = min(PBCHUNK, E - b0);
    for (int j = tid; j < cnt; j += 256) {
        int s = __builtin_nontemporal_load(&src[b0 + j]);
        int d = __builtin_nontemporal_load(&dst[b0 + j]);
        int bin = d >> 7;
        spack[j] = (unsigned)s | ((unsigned)(d & 127) << 17);
        sbin[j] = (unsigned short)bin;
        slrank[j] = (unsigned short)atomicAdd(&hist[bin], 1);
    }
    __syncthreads();
    for (int i = tid; i < nb; i += 256)
        base[i] = hist[i] ? atomicAdd(&cursor[i], hist[i]) : 0;
    __syncthreads();
    for (int j = tid; j < cnt; j += 256) {
        int bin = sbin[j];
        ebuf[(size_t)bin * WINSLOTS + base[bin] + slrank[j]] = spack[j];
    }
}

__global__ __launch_bounds__(256) void k_csrwin(const unsigned* __restrict__ ebuf,
                                                const int* __restrict__ cursor,
                                                int* __restrict__ csr,
                                                int2* __restrict__ offcnt,
                                                float* __restrict__ dinv, int n) {
    __shared__ int hist[WINSZ];
    __shared__ int lscan[WINSZ];
    __shared__ int sexcl[WINSZ];
    int b = blockIdx.x;
    int tid = threadIdx.x;
    if (tid < WINSZ) hist[tid] = 0;
    __syncthreads();
    int cnt = cursor[b];
    const unsigned* eb = ebuf + (size_t)b * WINSLOTS;
    for (int j = tid; j < cnt; j += 256)
        atomicAdd(&hist[eb[j] >> 17], 1);
    __syncthreads();
    int deg = (tid < WINSZ) ? hist[tid] : 0;
    if (tid < WINSZ) lscan[tid] = deg;
    __syncthreads();
    for (int off = 1; off < WINSZ; off <<= 1) {
        int y = (tid < WINSZ && tid >= off) ? lscan[tid - off] : 0;
        __syncthreads();
        if (tid < WINSZ) lscan[tid] += y;
        __syncthreads();
    }
    int gbase = b * WINSLOTS;
    if (tid < WINSZ) {
        int excl = lscan[tid] - deg;
        int v = b * WINSZ + tid;
        if (v < n) {
            offcnt[v] = make_int2(gbase + excl, deg);
            dinv[v] = rsqrtf((float)(deg + 1));
        }
        hist[tid] = 0;
        sexcl[tid] = excl;
    }
    __syncthreads();
    for (int j = tid; j < cnt; j += 256) {
        unsigned p = eb[j];
        int d7 = (int)(p >> 17);
        int lr = atomicAdd(&hist[d7], 1);
        csr[gbase + sexcl[d7] + lr] = (int)(p & 0x1FFFFu);
    }
}

// ---------------- MFMA bf16 GEMM: H' = (bf16(X) @ bf16(W1)) * dinv[row] ---
// A frag (16x16x32): lane l -> row=l&15, k=8*(l>>4)+j ; B: col=l&15, k same
// C/D: col=lane&15, row=4*(lane>>4)+reg   [m89-verified]

__global__ __launch_bounds__(256) void k_gemm_mfma(const float* __restrict__ X,
                                                   const float* __restrict__ W1,
                                                   const float* __restrict__ dinv,
                                                   unsigned short* __restrict__ H, int nrows) {
    __shared__ unsigned short xs[64][XP];    // X tile, bf16
    __shared__ unsigned short wt[128][XP];   // W^T: wt[n][k]
    int tid = threadIdx.x;
    int m0 = blockIdx.x * 64;
    // stage W^T: coalesced fp32 read of W1 row k, scattered LDS writes
    for (int i = tid; i < 2048; i += 256) {
        int elt = i * 8;
        int k = elt >> 7, n0 = elt & 127;            // W1[k][n0..n0+7]
        float4 a = *(const float4*)&W1[k * D + n0];
        float4 b = *(const float4*)&W1[k * D + n0 + 4];
        wt[n0 + 0][k] = f2bf(a.x); wt[n0 + 1][k] = f2bf(a.y);
        wt[n0 + 2][k] = f2bf(a.z); wt[n0 + 3][k] = f2bf(a.w);
        wt[n0 + 4][k] = f2bf(b.x); wt[n0 + 5][k] = f2bf(b.y);
        wt[n0 + 6][k] = f2bf(b.z); wt[n0 + 7][k] = f2bf(b.w);
    }
    // stage X tile (convert fp32 -> bf16)
    for (int i = tid; i < 2048; i += 256) {
        int elt = i * 4;
        int r = elt >> 7, c = elt & 127;
        int gr = m0 + r;
        float4 v = (gr < nrows) ? *(const float4*)&X[(size_t)gr * D + c]
                                : make_float4(0.f, 0.f, 0.f, 0.f);
        ushort4 bv;
        bv.x = f2bf(v.x); bv.y = f2bf(v.y); bv.z = f2bf(v.z); bv.w = f2bf(v.w);
        *(ushort4*)&xs[r][c] = bv;
    }
    __syncthreads();
    int wv = tid >> 6, lane = tid & 63;
    int lrow = lane & 15, lk = (lane >> 4) * 8;
    f32x4 acc[8];
#pragma unroll
    for (int i = 0; i < 8; ++i) acc[i] = (f32x4){0.f, 0.f, 0.f, 0.f};
#pragma unroll
    for (int kk = 0; kk < 128; kk += 32) {
        bf16x8 a = *(bf16x8*)&xs[wv * 16 + lrow][kk + lk];
#pragma unroll
        for (int nt = 0; nt < 8; ++nt) {
            bf16x8 b = *(bf16x8*)&wt[nt * 16 + lrow][kk + lk];
            acc[nt] = __builtin_amdgcn_mfma_f32_16x16x32_bf16(a, b, acc[nt], 0, 0, 0);
        }
    }
    int orow = m0 + wv * 16 + (lane >> 4) * 4;
    float dvr[4];
#pragma unroll
    for (int r = 0; r < 4; ++r) dvr[r] = (orow + r < nrows) ? dinv[orow + r] : 0.f;
#pragma unroll
    for (int nt = 0; nt < 8; ++nt) {
#pragma unroll
        for (int r = 0; r < 4; ++r) {
            int gr = orow + r;
            if (gr < nrows) H[(size_t)gr * D + nt * 16 + lrow] = f2bf(acc[nt][r] * dvr[r]);
        }
    }
}

// ---------------- layer-1 agg + relu + projection --------------------------
// H pre-scaled by dinv[src]: agg(v) = dv * (H'[v] + sum_e H'[s_e]).
// csr/offcnt are streamed once -> nontemporal (keep L2 for H rows).

__global__ __launch_bounds__(256) void k_agg_proj(const unsigned short* __restrict__ H,
                                                  const int2* __restrict__ offcnt,
                                                  const int* __restrict__ csr,
                                                  const float* __restrict__ dinv,
                                                  const float* __restrict__ bias,
                                                  const float* __restrict__ Weff,
                                                  float2* __restrict__ z, int n) {
    int wid = threadIdx.x >> 6;
    int lane = threadIdx.x & 63;
    int v = blockIdx.x * 4 + wid;
    if (v >= n) return;
    float dv = dinv[v];
    int l2 = lane * 2;
    unsigned us = *(const unsigned*)(H + (size_t)v * D + l2);
    float2 hs = bf2_to_f2(us);
    float2 acc = make_float2(hs.x, hs.y);     // self term: H'[v]
    int2v oc = __builtin_nontemporal_load((const int2v*)&offcnt[v]);
    int e = oc.x, eE = oc.x + oc.y;
    for (; e + 7 < eE; e += 8) {
        int s[8];
#pragma unroll
        for (int j = 0; j < 8; ++j) s[j] = __builtin_nontemporal_load(&csr[e + j]);
        unsigned u[8];
#pragma unroll
        for (int j = 0; j < 8; ++j) u[j] = *(const unsigned*)(H + (size_t)s[j] * D + l2);
#pragma unroll
        for (int j = 0; j < 8; ++j) {
            float2 h = bf2_to_f2(u[j]);
            acc.x += h.x; acc.y += h.y;
        }
    }
    for (; e + 3 < eE; e += 4) {
        int s0 = __builtin_nontemporal_load(&csr[e]);
        int s1 = __builtin_nontemporal_load(&csr[e + 1]);
        int s2 = __builtin_nontemporal_load(&csr[e + 2]);
        int s3 = __builtin_nontemporal_load(&csr[e + 3]);
        unsigned u0 = *(const unsigned*)(H + (size_t)s0 * D + l2);
        unsigned u1 = *(const unsigned*)(H + (size_t)s1 * D + l2);
        unsigned u2 = *(const unsigned*)(H + (size_t)s2 * D + l2);
        unsigned u3 = *(const unsigned*)(H + (size_t)s3 * D + l2);
        float2 h0 = bf2_to_f2(u0), h1 = bf2_to_f2(u1);
        float2 h2 = bf2_to_f2(u2), h3 = bf2_to_f2(u3);
        acc.x += h0.x + h1.x + h2.x + h3.x;
        acc.y += h0.y + h1.y + h2.y + h3.y;
    }
    for (; e < eE; ++e) {
        int s0 = __builtin_nontemporal_load(&csr[e]);
        unsigned u0 = *(const unsigned*)(H + (size_t)s0 * D + l2);
        float2 h0 = bf2_to_f2(u0);
        acc.x += h0.x; acc.y += h0.y;
    }
    float2 b = ((const float2*)bias)[lane];
    acc.x = fmaxf(acc.x * dv + b.x, 0.f);
    acc.y = fmaxf(acc.y * dv + b.y, 0.f);
    float4 wv = *(const float4*)&Weff[l2 * 2];
    float z0 = acc.x * wv.x + acc.y * wv.z;
    float z1 = acc.x * wv.y + acc.y * wv.w;
#pragma unroll
    for (int off = 32; off >= 1; off >>= 1) {
        z0 += __shfl_xor(z0, off, 64);
        z1 += __shfl_xor(z1, off, 64);
    }
    if (lane == 0) z[v] = make_float2(z0, z1);
}

// ---------------- fused layer-2 agg + mean-pool on projected z -----------
// per-wave private LDS accumulators; src/dst streamed nontemporal.

__global__ __launch_bounds__(256) void k_pool_edges(const float2* __restrict__ z,
                                                    const int* __restrict__ src,
                                                    const int* __restrict__ dst,
                                                    const float* __restrict__ dinv,
                                                    const int* __restrict__ batch,
                                                    float* __restrict__ tsum,
                                                    int* __restrict__ cnt,
                                                    int n, int E) {
    __shared__ float t[4][NGRAPH * 2];
    __shared__ int scnt[4][NGRAPH];
    int tid = threadIdx.x;
    int wv = tid >> 6;
    for (int j = tid; j < 4 * NGRAPH * 2; j += 256) ((float*)t)[j] = 0.f;
    for (int j = tid; j < 4 * NGRAPH; j += 256) ((int*)scnt)[j] = 0;
    __syncthreads();

    int i = (blockIdx.x * 256 + tid) * 4;
    int stride = POOLBLK * 256 * 4;
    for (; i < E; i += stride) {
        if (i + 3 < E) {
            int4v s4 = __builtin_nontemporal_load((const int4v*)&src[i]);
            int4v d4 = __builtin_nontemporal_load((const int4v*)&dst[i]);
            float w0 = dinv[s4.x] * dinv[d4.x];
            float w1 = dinv[s4.y] * dinv[d4.y];
            float w2 = dinv[s4.z] * dinv[d4.z];
            float w3 = dinv[s4.w] * dinv[d4.w];
            float2 z0 = z[s4.x], z1 = z[s4.y], z2 = z[s4.z], z3 = z[s4.w];
            int g0 = batch[d4.x], g1 = batch[d4.y], g2 = batch[d4.z], g3 = batch[d4.w];
            atomicAdd(&t[wv][g0 * 2],     w0 * z0.x);
            atomicAdd(&t[wv][g0 * 2 + 1], w0 * z0.y);
            atomicAdd(&t[wv][g1 * 2],     w1 * z1.x);
            atomicAdd(&t[wv][g1 * 2 + 1], w1 * z1.y);
            atomicAdd(&t[wv][g2 * 2],     w2 * z2.x);
            atomicAdd(&t[wv][g2 * 2 + 1], w2 * z2.y);
            atomicAdd(&t[wv][g3 * 2],     w3 * z3.x);
            atomicAdd(&t[wv][g3 * 2 + 1], w3 * z3.y);
        } else {
            for (int j = i; j < E; ++j) {
                int s = src[j], d = dst[j];
                float w = dinv[s] * dinv[d];
                float2 zv = z[s];
                int g = batch[d];
                atomicAdd(&t[wv][g * 2],     w * zv.x);
                atomicAdd(&t[wv][g * 2 + 1], w * zv.y);
            }
        }
    }
    for (int v = blockIdx.x * 256 + tid; v < n; v += POOLBLK * 256) {
        float dv = dinv[v];
        float2 zv = z[v];
        int g = batch[v];
        float w = dv * dv;
        atomicAdd(&t[wv][g * 2],     w * zv.x);
        atomicAdd(&t[wv][g * 2 + 1], w * zv.y);
        atomicAdd(&scnt[wv][g], 1);
    }
    __syncthreads();
    if (tid < NGRAPH * 2) {
        float s = t[0][tid] + t[1][tid] + t[2][tid] + t[3][tid];
        if (s != 0.f) atomicAdd(&tsum[tid], s);
    }
    if (tid < NGRAPH) {
        int s = scnt[0][tid] + scnt[1][tid] + scnt[2][tid] + scnt[3][tid];
        if (s) atomicAdd(&cnt[tid], s);
    }
}

__global__ void k_classify(const float* __restrict__ tsum, const int* __restrict__ cnt,
                           const float* __restrict__ beff, const float* __restrict__ bc,
                           float* __restrict__ out) {
    int t = threadIdx.x;
    if (t >= NGRAPH * 2) return;
    int g = t >> 1, c = t & 1;
    int cg = cnt[g];
    out[t] = cg ? (tsum[t] / (float)cg + beff[c]) : bc[c];
}

// ---------------- launch ----------------

extern "C" void kernel_launch(void* const* d_in, const int* in_sizes, int n_in,
                              void* d_out, int out_size, void* d_ws, size_t ws_size,
                              hipStream_t stream) {
    const float* x    = (const float*)d_in[0];
    const int*   ei   = (const int*)d_in[1];
    const int*   batch= (const int*)d_in[2];
    const float* W1   = (const float*)d_in[3];
    const float* b1   = (const float*)d_in[4];
    const float* W2   = (const float*)d_in[5];
    const float* b2   = (const float*)d_in[6];
    const float* Wc   = (const float*)d_in[7];
    const float* bc   = (const float*)d_in[8];

    const int n = in_sizes[0] / D;       // 100000
    const int E = in_sizes[1] / 2;       // 3200000
    const int* src = ei;
    const int* dst = ei + E;
    const int nb = (n + WINSZ - 1) / WINSZ;   // 782 dst-windows

    char* ws = (char*)d_ws;
    size_t off = 0;
    auto carve = [&](size_t bytes) -> char* {
        char* p = ws + off;
        off = (off + bytes + 255) & ~(size_t)255;
        return p;
    };
    unsigned short* bufBF = (unsigned short*)carve((size_t)n * D * 2);   // H' (bf16, dinv-scaled)
    float2* z     = (float2*)carve((size_t)n * 8);                       // projected h1
    unsigned* ebuf= (unsigned*)carve((size_t)nb * WINSLOTS * 4);         // windowed edges
    int*   csr    = (int*)  carve((size_t)nb * WINSLOTS * 4);            // windowed CSR
    // zero-region: cursor | tsum | cnt  (zeroed by k_prep)
    const int zero_words = NBMAX + NGRAPH * 2 + NGRAPH;
    int*   cursor = (int*)  carve(zero_words * 4);
    float* tsum   = (float*)(cursor + NBMAX);
    int*   cnt    = (int*)  (tsum + NGRAPH * 2);
    int2*  offcnt = (int2*) carve((size_t)n * 8);
    float* dinv   = (float*)carve((size_t)n * 4);
    float* Weff   = (float*)carve(D * 2 * 4);
    float* beff   = (float*)carve(2 * 4);

    // prep (Weff/beff + zeroing) then CSR build
    k_prep<<<1, 256, 0, stream>>>(W2, Wc, b2, bc, Weff, beff, cursor, zero_words);
    k_part<<<(E + PBCHUNK - 1) / PBCHUNK, 256, 0, stream>>>(src, dst, cursor, ebuf, E, nb);
    k_csrwin<<<nb, 256, 0, stream>>>(ebuf, cursor, csr, offcnt, dinv, n);

    // layer 1 GEMM (MFMA bf16, in-kernel W1 conversion), output scaled by dinv
    k_gemm_mfma<<<(n + 63) / 64, 256, 0, stream>>>(x, W1, dinv, bufBF, n);
    // layer-1 agg (unweighted sum of pre-scaled rows) + relu + project to z
    k_agg_proj<<<(n + 3) / 4, 256, 0, stream>>>(bufBF, offcnt, csr, dinv, b1, Weff, z, n);

    // fused layer-2 agg + mean-pool on z (raw edge stream)
    k_pool_edges<<<POOLBLK, 256, 0, stream>>>(z, src, dst, dinv, batch, tsum, cnt, n, E);
    k_classify<<<1, 128, 0, stream>>>(tsum, cnt, beff, bc, (float*)d_out);
}

// Round 16
// 293.776 us; speedup vs baseline: 1.1094x; 1.1094x over previous
//
#include <hip/hip_runtime.h>
#include <hip/hip_bf16.h>

#define D 128
#define NGRAPH 64
#define POOLBLK 256     // blocks in k_pool_edges
#define PBCHUNK 4096    // edges per block in k_part
#define WINSZ 256       // nodes per dst-window
#define WINSLOTS 16384  // edge slots per window (mean ~8184, 2x headroom)
#define XP 136          // padded LDS row (bf16) -> 2-way bank aliasing only

typedef __attribute__((ext_vector_type(4))) float f32x4;
typedef __attribute__((ext_vector_type(8))) short bf16x8;

__device__ __forceinline__ unsigned short f2bf(float f) {
    union { float f; unsigned int i; } u; u.f = f;
    unsigned int r = u.i + 0x7fffu + ((u.i >> 16) & 1u);   // round-to-nearest-even
    return (unsigned short)(r >> 16);
}
__device__ __forceinline__ float2 bf2_to_f2(unsigned int u) {
    union { unsigned int i; float f; } a, b;
    a.i = u << 16;            // low ushort  = element 0
    b.i = u & 0xffff0000u;    // high ushort = element 1
    return make_float2(a.f, b.f);
}

// ---------------- CSR build: windowed counting sort ----------------------
// block 0 additionally folds Weff = W2@Wc, beff = b2@Wc + bc (consumed 2
// kernels later -> ordering guaranteed by kernel boundaries).

__global__ __launch_bounds__(256) void k_part(const int* __restrict__ src,
                                              const int* __restrict__ dst,
                                              int* __restrict__ cursor,
                                              unsigned* __restrict__ ebuf,
                                              const float* __restrict__ W2,
                                              const float* __restrict__ Wc,
                                              const float* __restrict__ b2,
                                              const float* __restrict__ bc,
                                              float* __restrict__ Weff,
                                              float* __restrict__ beff,
                                              int E, int nb) {
    __shared__ unsigned spack[PBCHUNK];
    __shared__ unsigned short sbin[PBCHUNK];
    __shared__ unsigned short slrank[PBCHUNK];
    __shared__ int hist[400];
    __shared__ int base[400];
    int tid = threadIdx.x;
    for (int i = tid; i < nb; i += 256) hist[i] = 0;
    __syncthreads();
    int b0 = blockIdx.x * PBCHUNK;
    int cnt = min(PBCHUNK, E - b0);
    for (int j = tid; j < cnt; j += 256) {
        int s = __builtin_nontemporal_load(&src[b0 + j]);
        int d = __builtin_nontemporal_load(&dst[b0 + j]);
        int bin = d >> 8;
        spack[j] = (unsigned)s | ((unsigned)(d & 255) << 17);
        sbin[j] = (unsigned short)bin;
        slrank[j] = (unsigned short)atomicAdd(&hist[bin], 1);
    }
    __syncthreads();
    for (int i = tid; i < nb; i += 256)
        base[i] = hist[i] ? atomicAdd(&cursor[i], hist[i]) : 0;
    __syncthreads();
    for (int j = tid; j < cnt; j += 256) {
        int bin = sbin[j];
        ebuf[(size_t)bin * WINSLOTS + base[bin] + slrank[j]] = spack[j];
    }
    // folded prep (block 0 only)
    if (blockIdx.x == 0) {
        int i = tid >> 1, c = tid & 1;
        float acc = 0.f;
        for (int k = 0; k < D; ++k) acc += W2[i * D + k] * Wc[k * 2 + c];
        Weff[i * 2 + c] = acc;
        if (i == 0) {
            float s = 0.f;
            for (int k = 0; k < D; ++k) s += b2[k] * Wc[k * 2 + c];
            beff[c] = s + bc[c];
        }
    }
}

__global__ __launch_bounds__(256) void k_csrwin(const unsigned* __restrict__ ebuf,
                                                const int* __restrict__ cursor,
                                                int* __restrict__ csr,
                                                int2* __restrict__ offcnt,
                                                float* __restrict__ dinv, int n) {
    __shared__ int hist[WINSZ];
    __shared__ int lscan[WINSZ];
    __shared__ int sexcl[WINSZ];
    int b = blockIdx.x;
    int tid = threadIdx.x;
    hist[tid] = 0;
    __syncthreads();
    int cnt = cursor[b];
    const unsigned* eb = ebuf + (size_t)b * WINSLOTS;
    for (int j = tid; j < cnt; j += 256)
        atomicAdd(&hist[eb[j] >> 17], 1);
    __syncthreads();
    int deg = hist[tid];
    lscan[tid] = deg;
    __syncthreads();
    for (int off = 1; off < 256; off <<= 1) {
        int y = (tid >= off) ? lscan[tid - off] : 0;
        __syncthreads();
        lscan[tid] += y;
        __syncthreads();
    }
    int excl = lscan[tid] - deg;
    int v = b * WINSZ + tid;
    int gbase = b * WINSLOTS;
    if (v < n) {
        offcnt[v] = make_int2(gbase + excl, deg);
        dinv[v] = rsqrtf((float)(deg + 1));
    }
    hist[tid] = 0;
    sexcl[tid] = excl;
    __syncthreads();
    for (int j = tid; j < cnt; j += 256) {
        unsigned p = eb[j];
        int d8 = (int)(p >> 17);
        int lr = atomicAdd(&hist[d8], 1);
        csr[gbase + sexcl[d8] + lr] = (int)(p & 0x1FFFFu);
    }
}

// ---------------- MFMA bf16 GEMM: H' = (bf16(X) @ bf16(W1)) * dinv[row] ---
// A frag (16x16x32): lane l -> row=l&15, k=8*(l>>4)+j ; B: col=l&15, k same
// C/D: col=lane&15, row=4*(lane>>4)+reg   [m89-verified]

__global__ __launch_bounds__(256) void k_gemm_mfma(const float* __restrict__ X,
                                                   const float* __restrict__ W1,
                                                   const float* __restrict__ dinv,
                                                   unsigned short* __restrict__ H, int nrows) {
    __shared__ unsigned short xs[64][XP];    // X tile, bf16
    __shared__ unsigned short wt[128][XP];   // W^T: wt[n][k]
    int tid = threadIdx.x;
    int m0 = blockIdx.x * 64;
    // stage W^T: coalesced fp32 read of W1 row k, scattered LDS writes
    for (int i = tid; i < 2048; i += 256) {
        int elt = i * 8;
        int k = elt >> 7, n0 = elt & 127;            // W1[k][n0..n0+7]
        float4 a = *(const float4*)&W1[k * D + n0];
        float4 b = *(const float4*)&W1[k * D + n0 + 4];
        wt[n0 + 0][k] = f2bf(a.x); wt[n0 + 1][k] = f2bf(a.y);
        wt[n0 + 2][k] = f2bf(a.z); wt[n0 + 3][k] = f2bf(a.w);
        wt[n0 + 4][k] = f2bf(b.x); wt[n0 + 5][k] = f2bf(b.y);
        wt[n0 + 6][k] = f2bf(b.z); wt[n0 + 7][k] = f2bf(b.w);
    }
    // stage X tile (convert fp32 -> bf16)
    for (int i = tid; i < 2048; i += 256) {
        int elt = i * 4;
        int r = elt >> 7, c = elt & 127;
        int gr = m0 + r;
        float4 v = (gr < nrows) ? *(const float4*)&X[(size_t)gr * D + c]
                                : make_float4(0.f, 0.f, 0.f, 0.f);
        ushort4 bv;
        bv.x = f2bf(v.x); bv.y = f2bf(v.y); bv.z = f2bf(v.z); bv.w = f2bf(v.w);
        *(ushort4*)&xs[r][c] = bv;
    }
    __syncthreads();
    int wv = tid >> 6, lane = tid & 63;
    int lrow = lane & 15, lk = (lane >> 4) * 8;
    f32x4 acc[8];
#pragma unroll
    for (int i = 0; i < 8; ++i) acc[i] = (f32x4){0.f, 0.f, 0.f, 0.f};
#pragma unroll
    for (int kk = 0; kk < 128; kk += 32) {
        bf16x8 a = *(bf16x8*)&xs[wv * 16 + lrow][kk + lk];
#pragma unroll
        for (int nt = 0; nt < 8; ++nt) {
            bf16x8 b = *(bf16x8*)&wt[nt * 16 + lrow][kk + lk];
            acc[nt] = __builtin_amdgcn_mfma_f32_16x16x32_bf16(a, b, acc[nt], 0, 0, 0);
        }
    }
    int orow = m0 + wv * 16 + (lane >> 4) * 4;
    float dvr[4];
#pragma unroll
    for (int r = 0; r < 4; ++r) dvr[r] = (orow + r < nrows) ? dinv[orow + r] : 0.f;
#pragma unroll
    for (int nt = 0; nt < 8; ++nt) {
#pragma unroll
        for (int r = 0; r < 4; ++r) {
            int gr = orow + r;
            if (gr < nrows) H[(size_t)gr * D + nt * 16 + lrow] = f2bf(acc[nt][r] * dvr[r]);
        }
    }
}

// ---------------- layer-1 agg + relu + projection --------------------------
// H pre-scaled by dinv[src]: agg(v) = dv * (H'[v] + sum_e H'[s_e]).
// 16-deep ILP; csr loads are wave-uniform -> scalar-path broadcasts.

__global__ __launch_bounds__(256) void k_agg_proj(const unsigned short* __restrict__ H,
                                                  const int2* __restrict__ offcnt,
                                                  const int* __restrict__ csr,
                                                  const float* __restrict__ dinv,
                                                  const float* __restrict__ bias,
                                                  const float* __restrict__ Weff,
                                                  float2* __restrict__ z, int n) {
    int wid = threadIdx.x >> 6;
    int lane = threadIdx.x & 63;
    int v = blockIdx.x * 4 + wid;
    if (v >= n) return;
    float dv = dinv[v];
    int l2 = lane * 2;
    unsigned us = *(const unsigned*)(H + (size_t)v * D + l2);
    float2 hs = bf2_to_f2(us);
    float2 acc = make_float2(hs.x, hs.y);     // self term: H'[v]
    int2 oc = offcnt[v];
    int e = oc.x, eE = oc.x + oc.y;
    for (; e + 15 < eE; e += 16) {
        int s[16];
#pragma unroll
        for (int j = 0; j < 16; ++j) s[j] = csr[e + j];
        unsigned u[16];
#pragma unroll
        for (int j = 0; j < 16; ++j) u[j] = *(const unsigned*)(H + (size_t)s[j] * D + l2);
#pragma unroll
        for (int j = 0; j < 16; ++j) {
            float2 h = bf2_to_f2(u[j]);
            acc.x += h.x; acc.y += h.y;
        }
    }
    for (; e + 7 < eE; e += 8) {
        int s[8];
#pragma unroll
        for (int j = 0; j < 8; ++j) s[j] = csr[e + j];
        unsigned u[8];
#pragma unroll
        for (int j = 0; j < 8; ++j) u[j] = *(const unsigned*)(H + (size_t)s[j] * D + l2);
#pragma unroll
        for (int j = 0; j < 8; ++j) {
            float2 h = bf2_to_f2(u[j]);
            acc.x += h.x; acc.y += h.y;
        }
    }
    for (; e + 3 < eE; e += 4) {
        int s0 = csr[e], s1 = csr[e + 1], s2 = csr[e + 2], s3 = csr[e + 3];
        unsigned u0 = *(const unsigned*)(H + (size_t)s0 * D + l2);
        unsigned u1 = *(const unsigned*)(H + (size_t)s1 * D + l2);
        unsigned u2 = *(const unsigned*)(H + (size_t)s2 * D + l2);
        unsigned u3 = *(const unsigned*)(H + (size_t)s3 * D + l2);
        float2 h0 = bf2_to_f2(u0), h1 = bf2_to_f2(u1);
        float2 h2 = bf2_to_f2(u2), h3 = bf2_to_f2(u3);
        acc.x += h0.x + h1.x + h2.x + h3.x;
        acc.y += h0.y + h1.y + h2.y + h3.y;
    }
    for (; e < eE; ++e) {
        int s0 = csr[e];
        unsigned u0 = *(const unsigned*)(H + (size_t)s0 * D + l2);
        float2 h0 = bf2_to_f2(u0);
        acc.x += h0.x; acc.y += h0.y;
    }
    float2 b = ((const float2*)bias)[lane];
    acc.x = fmaxf(acc.x * dv + b.x, 0.f);
    acc.y = fmaxf(acc.y * dv + b.y, 0.f);
    float4 wv = *(const float4*)&Weff[l2 * 2];
    float z0 = acc.x * wv.x + acc.y * wv.z;
    float z1 = acc.x * wv.y + acc.y * wv.w;
#pragma unroll
    for (int off = 32; off >= 1; off >>= 1) {
        z0 += __shfl_xor(z0, off, 64);
        z1 += __shfl_xor(z1, off, 64);
    }
    if (lane == 0) z[v] = make_float2(z0, z1);
}

// ---------------- fused layer-2 agg + mean-pool on projected z -----------
// per-wave private LDS accumulators (4x less same-address contention)

__global__ __launch_bounds__(256) void k_pool_edges(const float2* __restrict__ z,
                                                    const int* __restrict__ src,
                                                    const int* __restrict__ dst,
                                                    const float* __restrict__ dinv,
                                                    const int* __restrict__ batch,
                                                    float* __restrict__ tsum,
                                                    int* __restrict__ cnt,
                                                    int n, int E) {
    __shared__ float t[4][NGRAPH * 2];
    __shared__ int scnt[4][NGRAPH];
    int tid = threadIdx.x;
    int wv = tid >> 6;
    for (int j = tid; j < 4 * NGRAPH * 2; j += 256) ((float*)t)[j] = 0.f;
    for (int j = tid; j < 4 * NGRAPH; j += 256) ((int*)scnt)[j] = 0;
    __syncthreads();

    int i = (blockIdx.x * 256 + tid) * 4;
    int stride = POOLBLK * 256 * 4;
    for (; i < E; i += stride) {
        if (i + 3 < E) {
            int4 s4 = *(const int4*)&src[i];
            int4 d4 = *(const int4*)&dst[i];
            float w0 = dinv[s4.x] * dinv[d4.x];
            float w1 = dinv[s4.y] * dinv[d4.y];
            float w2 = dinv[s4.z] * dinv[d4.z];
            float w3 = dinv[s4.w] * dinv[d4.w];
            float2 z0 = z[s4.x], z1 = z[s4.y], z2 = z[s4.z], z3 = z[s4.w];
            int g0 = batch[d4.x], g1 = batch[d4.y], g2 = batch[d4.z], g3 = batch[d4.w];
            atomicAdd(&t[wv][g0 * 2],     w0 * z0.x);
            atomicAdd(&t[wv][g0 * 2 + 1], w0 * z0.y);
            atomicAdd(&t[wv][g1 * 2],     w1 * z1.x);
            atomicAdd(&t[wv][g1 * 2 + 1], w1 * z1.y);
            atomicAdd(&t[wv][g2 * 2],     w2 * z2.x);
            atomicAdd(&t[wv][g2 * 2 + 1], w2 * z2.y);
            atomicAdd(&t[wv][g3 * 2],     w3 * z3.x);
            atomicAdd(&t[wv][g3 * 2 + 1], w3 * z3.y);
        } else {
            for (int j = i; j < E; ++j) {
                int s = src[j], d = dst[j];
                float w = dinv[s] * dinv[d];
                float2 zv = z[s];
                int g = batch[d];
                atomicAdd(&t[wv][g * 2],     w * zv.x);
                atomicAdd(&t[wv][g * 2 + 1], w * zv.y);
            }
        }
    }
    for (int v = blockIdx.x * 256 + tid; v < n; v += POOLBLK * 256) {
        float dv = dinv[v];
        float2 zv = z[v];
        int g = batch[v];
        float w = dv * dv;
        atomicAdd(&t[wv][g * 2],     w * zv.x);
        atomicAdd(&t[wv][g * 2 + 1], w * zv.y);
        atomicAdd(&scnt[wv][g], 1);
    }
    __syncthreads();
    if (tid < NGRAPH * 2) {
        float s = t[0][tid] + t[1][tid] + t[2][tid] + t[3][tid];
        if (s != 0.f) atomicAdd(&tsum[tid], s);
    }
    if (tid < NGRAPH) {
        int s = scnt[0][tid] + scnt[1][tid] + scnt[2][tid] + scnt[3][tid];
        if (s) atomicAdd(&cnt[tid], s);
    }
}

__global__ void k_classify(const float* __restrict__ tsum, const int* __restrict__ cnt,
                           const float* __restrict__ beff, const float* __restrict__ bc,
                           float* __restrict__ out) {
    int t = threadIdx.x;
    if (t >= NGRAPH * 2) return;
    int g = t >> 1, c = t & 1;
    int cg = cnt[g];
    out[t] = cg ? (tsum[t] / (float)cg + beff[c]) : bc[c];
}

// ---------------- launch ----------------

extern "C" void kernel_launch(void* const* d_in, const int* in_sizes, int n_in,
                              void* d_out, int out_size, void* d_ws, size_t ws_size,
                              hipStream_t stream) {
    const float* x    = (const float*)d_in[0];
    const int*   ei   = (const int*)d_in[1];
    const int*   batch= (const int*)d_in[2];
    const float* W1   = (const float*)d_in[3];
    const float* b1   = (const float*)d_in[4];
    const float* W2   = (const float*)d_in[5];
    const float* b2   = (const float*)d_in[6];
    const float* Wc   = (const float*)d_in[7];
    const float* bc   = (const float*)d_in[8];

    const int n = in_sizes[0] / D;       // 100000
    const int E = in_sizes[1] / 2;       // 3200000
    const int* src = ei;
    const int* dst = ei + E;
    const int nb = (n + WINSZ - 1) / WINSZ;   // 391 dst-windows

    char* ws = (char*)d_ws;
    size_t off = 0;
    auto carve = [&](size_t bytes) -> char* {
        char* p = ws + off;
        off = (off + bytes + 255) & ~(size_t)255;
        return p;
    };
    unsigned short* bufBF = (unsigned short*)carve((size_t)n * D * 2);   // H' (bf16, dinv-scaled)
    float2* z     = (float2*)carve((size_t)n * 8);                       // projected h1
    unsigned* ebuf= (unsigned*)carve((size_t)nb * WINSLOTS * 4);         // windowed edges
    int*   csr    = (int*)  carve((size_t)nb * WINSLOTS * 4);            // windowed CSR
    // zero-region: cursor | tsum | cnt  (one memset)
    const int zero_words = 512 + NGRAPH * 2 + NGRAPH;
    int*   cursor = (int*)  carve(zero_words * 4);
    float* tsum   = (float*)(cursor + 512);
    int*   cnt    = (int*)  (tsum + NGRAPH * 2);
    int2*  offcnt = (int2*) carve((size_t)n * 8);
    float* dinv   = (float*)carve((size_t)n * 4);
    float* Weff   = (float*)carve(D * 2 * 4);
    float* beff   = (float*)carve(2 * 4);

    hipMemsetAsync(cursor, 0, zero_words * 4, stream);

    // CSR build (windowed counting sort); k_part block 0 also folds Weff/beff
    k_part<<<(E + PBCHUNK - 1) / PBCHUNK, 256, 0, stream>>>(src, dst, cursor, ebuf,
                                                            W2, Wc, b2, bc, Weff, beff, E, nb);
    k_csrwin<<<nb, 256, 0, stream>>>(ebuf, cursor, csr, offcnt, dinv, n);

    // layer 1 GEMM (MFMA bf16, in-kernel W1 conversion), output scaled by dinv
    k_gemm_mfma<<<(n + 63) / 64, 256, 0, stream>>>(x, W1, dinv, bufBF, n);
    // layer-1 agg (unweighted sum of pre-scaled rows) + relu + project to z
    k_agg_proj<<<(n + 3) / 4, 256, 0, stream>>>(bufBF, offcnt, csr, dinv, b1, Weff, z, n);

    // fused layer-2 agg + mean-pool on z (raw edge stream)
    k_pool_edges<<<POOLBLK, 256, 0, stream>>>(z, src, dst, dinv, batch, tsum, cnt, n, E);
    k_classify<<<1, 128, 0, stream>>>(tsum, cnt, beff, bc, (float*)d_out);
}

// Round 17
// 281.555 us; speedup vs baseline: 1.1576x; 1.0434x over previous
//
#include <hip/hip_runtime.h>
#include <hip/hip_bf16.h>

#define D 128
#define NGRAPH 64
#define POOLBLK 512     // blocks in k_pool_edges
#define PBCHUNK 4096    // edges per block in k_part
#define WINSZ 256       // nodes per dst-window
#define WINSLOTS 16384  // edge slots per window (mean ~8184, 2x headroom)
#define CSTAGE 12288    // LDS-staged edges per window in k_csrwin (48KB)
#define XP 136          // padded LDS row (bf16) -> 2-way bank aliasing only

typedef __attribute__((ext_vector_type(4))) float f32x4;
typedef __attribute__((ext_vector_type(8))) short bf16x8;

__device__ __forceinline__ unsigned short f2bf(float f) {
    union { float f; unsigned int i; } u; u.f = f;
    unsigned int r = u.i + 0x7fffu + ((u.i >> 16) & 1u);   // round-to-nearest-even
    return (unsigned short)(r >> 16);
}
__device__ __forceinline__ float2 bf2_to_f2(unsigned int u) {
    union { unsigned int i; float f; } a, b;
    a.i = u << 16;            // low ushort  = element 0
    b.i = u & 0xffff0000u;    // high ushort = element 1
    return make_float2(a.f, b.f);
}

// ---------------- CSR build: windowed counting sort ----------------------
// block 0 additionally folds Weff = W2@Wc, beff = b2@Wc + bc.

__global__ __launch_bounds__(256) void k_part(const int* __restrict__ src,
                                              const int* __restrict__ dst,
                                              int* __restrict__ cursor,
                                              unsigned* __restrict__ ebuf,
                                              const float* __restrict__ W2,
                                              const float* __restrict__ Wc,
                                              const float* __restrict__ b2,
                                              const float* __restrict__ bc,
                                              float* __restrict__ Weff,
                                              float* __restrict__ beff,
                                              int E, int nb) {
    __shared__ unsigned spack[PBCHUNK];
    __shared__ unsigned short sbin[PBCHUNK];
    __shared__ unsigned short slrank[PBCHUNK];
    __shared__ int hist[400];
    __shared__ int base[400];
    int tid = threadIdx.x;
    for (int i = tid; i < nb; i += 256) hist[i] = 0;
    __syncthreads();
    int b0 = blockIdx.x * PBCHUNK;
    int cnt = min(PBCHUNK, E - b0);
    for (int j = tid; j < cnt; j += 256) {
        int s = __builtin_nontemporal_load(&src[b0 + j]);
        int d = __builtin_nontemporal_load(&dst[b0 + j]);
        int bin = d >> 8;
        spack[j] = (unsigned)s | ((unsigned)(d & 255) << 17);
        sbin[j] = (unsigned short)bin;
        slrank[j] = (unsigned short)atomicAdd(&hist[bin], 1);
    }
    __syncthreads();
    for (int i = tid; i < nb; i += 256)
        base[i] = hist[i] ? atomicAdd(&cursor[i], hist[i]) : 0;
    __syncthreads();
    for (int j = tid; j < cnt; j += 256) {
        int bin = sbin[j];
        ebuf[(size_t)bin * WINSLOTS + base[bin] + slrank[j]] = spack[j];
    }
    // folded prep (block 0 only)
    if (blockIdx.x == 0) {
        int i = tid >> 1, c = tid & 1;
        float acc = 0.f;
        for (int k = 0; k < D; ++k) acc += W2[i * D + k] * Wc[k * 2 + c];
        Weff[i * 2 + c] = acc;
        if (i == 0) {
            float s = 0.f;
            for (int k = 0; k < D; ++k) s += b2[k] * Wc[k * 2 + c];
            beff[c] = s + bc[c];
        }
    }
}

__global__ __launch_bounds__(256) void k_csrwin(const unsigned* __restrict__ ebuf,
                                                const int* __restrict__ cursor,
                                                int* __restrict__ csr,
                                                int2* __restrict__ offcnt,
                                                float* __restrict__ dinv, int n) {
    __shared__ int hist[WINSZ];
    __shared__ int lscan[WINSZ];
    __shared__ int sexcl[WINSZ];
    __shared__ unsigned sstage[CSTAGE];
    int b = blockIdx.x;
    int tid = threadIdx.x;
    hist[tid] = 0;
    __syncthreads();
    int cnt = cursor[b];
    int stcnt = min(cnt, CSTAGE);
    const unsigned* eb = ebuf + (size_t)b * WINSLOTS;
    // histogram pass doubles as LDS staging
    for (int j = tid; j < cnt; j += 256) {
        unsigned p = eb[j];
        if (j < CSTAGE) sstage[j] = p;
        atomicAdd(&hist[p >> 17], 1);
    }
    __syncthreads();
    int deg = hist[tid];
    lscan[tid] = deg;
    __syncthreads();
    for (int off = 1; off < 256; off <<= 1) {
        int y = (tid >= off) ? lscan[tid - off] : 0;
        __syncthreads();
        lscan[tid] += y;
        __syncthreads();
    }
    int excl = lscan[tid] - deg;
    int v = b * WINSZ + tid;
    int gbase = b * WINSLOTS;
    if (v < n) {
        offcnt[v] = make_int2(gbase + excl, deg);
        dinv[v] = rsqrtf((float)(deg + 1));
    }
    hist[tid] = 0;
    sexcl[tid] = excl;
    __syncthreads();
    for (int j = tid; j < stcnt; j += 256) {
        unsigned p = sstage[j];
        int d8 = (int)(p >> 17);
        int lr = atomicAdd(&hist[d8], 1);
        csr[gbase + sexcl[d8] + lr] = (int)(p & 0x1FFFFu);
    }
    for (int j = stcnt + tid; j < cnt; j += 256) {   // overflow fallback (rare)
        unsigned p = eb[j];
        int d8 = (int)(p >> 17);
        int lr = atomicAdd(&hist[d8], 1);
        csr[gbase + sexcl[d8] + lr] = (int)(p & 0x1FFFFu);
    }
}

// ---------------- MFMA bf16 GEMM: H' = (bf16(X) @ bf16(W1)) * dinv[row] ---
// A fragments loaded directly from global X (fp32->bf16 in-reg); W^T in LDS.
// A frag (16x16x32): lane l -> row=l&15, k=8*(l>>4)+j ; B: col=l&15, k same
// C/D: col=lane&15, row=4*(lane>>4)+reg   [m89-verified]

__global__ __launch_bounds__(256) void k_gemm_mfma(const float* __restrict__ X,
                                                   const float* __restrict__ W1,
                                                   const float* __restrict__ dinv,
                                                   unsigned short* __restrict__ H, int nrows) {
    __shared__ unsigned short wt[128][XP];   // W^T: wt[n][k]
    int tid = threadIdx.x;
    int m0 = blockIdx.x * 64;
    // stage W^T: coalesced fp32 read of W1 row k, scattered LDS writes
    for (int i = tid; i < 2048; i += 256) {
        int elt = i * 8;
        int k = elt >> 7, n0 = elt & 127;            // W1[k][n0..n0+7]
        float4 a = *(const float4*)&W1[k * D + n0];
        float4 b = *(const float4*)&W1[k * D + n0 + 4];
        wt[n0 + 0][k] = f2bf(a.x); wt[n0 + 1][k] = f2bf(a.y);
        wt[n0 + 2][k] = f2bf(a.z); wt[n0 + 3][k] = f2bf(a.w);
        wt[n0 + 4][k] = f2bf(b.x); wt[n0 + 5][k] = f2bf(b.y);
        wt[n0 + 6][k] = f2bf(b.z); wt[n0 + 7][k] = f2bf(b.w);
    }
    __syncthreads();
    int wv = tid >> 6, lane = tid & 63;
    int lrow = lane & 15, lk = (lane >> 4) * 8;
    int arow = m0 + wv * 16 + lrow;              // output row this lane's A-frag feeds
    const float* xrow = X + (size_t)min(arow, nrows - 1) * D;
    f32x4 acc[8];
#pragma unroll
    for (int i = 0; i < 8; ++i) acc[i] = (f32x4){0.f, 0.f, 0.f, 0.f};
#pragma unroll
    for (int kk = 0; kk < 128; kk += 32) {
        float4 a0 = *(const float4*)&xrow[kk + lk];
        float4 a1 = *(const float4*)&xrow[kk + lk + 4];
        bf16x8 a;
        a[0] = (short)f2bf(a0.x); a[1] = (short)f2bf(a0.y);
        a[2] = (short)f2bf(a0.z); a[3] = (short)f2bf(a0.w);
        a[4] = (short)f2bf(a1.x); a[5] = (short)f2bf(a1.y);
        a[6] = (short)f2bf(a1.z); a[7] = (short)f2bf(a1.w);
#pragma unroll
        for (int nt = 0; nt < 8; ++nt) {
            bf16x8 b = *(bf16x8*)&wt[nt * 16 + lrow][kk + lk];
            acc[nt] = __builtin_amdgcn_mfma_f32_16x16x32_bf16(a, b, acc[nt], 0, 0, 0);
        }
    }
    int orow = m0 + wv * 16 + (lane >> 4) * 4;
    float dvr[4];
#pragma unroll
    for (int r = 0; r < 4; ++r) dvr[r] = (orow + r < nrows) ? dinv[orow + r] : 0.f;
#pragma unroll
    for (int nt = 0; nt < 8; ++nt) {
#pragma unroll
        for (int r = 0; r < 4; ++r) {
            int gr = orow + r;
            if (gr < nrows) H[(size_t)gr * D + nt * 16 + lrow] = f2bf(acc[nt][r] * dvr[r]);
        }
    }
}

// ---------------- layer-1 agg + relu + projection --------------------------
// H pre-scaled by dinv[src]: agg(v) = dv * (H'[v] + sum_e H'[s_e]).

__global__ __launch_bounds__(256) void k_agg_proj(const unsigned short* __restrict__ H,
                                                  const int2* __restrict__ offcnt,
                                                  const int* __restrict__ csr,
                                                  const float* __restrict__ dinv,
                                                  const float* __restrict__ bias,
                                                  const float* __restrict__ Weff,
                                                  float2* __restrict__ z, int n) {
    int wid = threadIdx.x >> 6;
    int lane = threadIdx.x & 63;
    int v = blockIdx.x * 4 + wid;
    if (v >= n) return;
    float dv = dinv[v];
    int l2 = lane * 2;
    unsigned us = *(const unsigned*)(H + (size_t)v * D + l2);
    float2 hs = bf2_to_f2(us);
    float2 acc = make_float2(hs.x, hs.y);     // self term: H'[v]
    int2 oc = offcnt[v];
    int e = oc.x, eE = oc.x + oc.y;
    for (; e + 15 < eE; e += 16) {
        int s[16];
#pragma unroll
        for (int j = 0; j < 16; ++j) s[j] = csr[e + j];
        unsigned u[16];
#pragma unroll
        for (int j = 0; j < 16; ++j) u[j] = *(const unsigned*)(H + (size_t)s[j] * D + l2);
#pragma unroll
        for (int j = 0; j < 16; ++j) {
            float2 h = bf2_to_f2(u[j]);
            acc.x += h.x; acc.y += h.y;
        }
    }
    for (; e + 7 < eE; e += 8) {
        int s[8];
#pragma unroll
        for (int j = 0; j < 8; ++j) s[j] = csr[e + j];
        unsigned u[8];
#pragma unroll
        for (int j = 0; j < 8; ++j) u[j] = *(const unsigned*)(H + (size_t)s[j] * D + l2);
#pragma unroll
        for (int j = 0; j < 8; ++j) {
            float2 h = bf2_to_f2(u[j]);
            acc.x += h.x; acc.y += h.y;
        }
    }
    for (; e + 3 < eE; e += 4) {
        int s0 = csr[e], s1 = csr[e + 1], s2 = csr[e + 2], s3 = csr[e + 3];
        unsigned u0 = *(const unsigned*)(H + (size_t)s0 * D + l2);
        unsigned u1 = *(const unsigned*)(H + (size_t)s1 * D + l2);
        unsigned u2 = *(const unsigned*)(H + (size_t)s2 * D + l2);
        unsigned u3 = *(const unsigned*)(H + (size_t)s3 * D + l2);
        float2 h0 = bf2_to_f2(u0), h1 = bf2_to_f2(u1);
        float2 h2 = bf2_to_f2(u2), h3 = bf2_to_f2(u3);
        acc.x += h0.x + h1.x + h2.x + h3.x;
        acc.y += h0.y + h1.y + h2.y + h3.y;
    }
    for (; e < eE; ++e) {
        int s0 = csr[e];
        unsigned u0 = *(const unsigned*)(H + (size_t)s0 * D + l2);
        float2 h0 = bf2_to_f2(u0);
        acc.x += h0.x; acc.y += h0.y;
    }
    float2 b = ((const float2*)bias)[lane];
    acc.x = fmaxf(acc.x * dv + b.x, 0.f);
    acc.y = fmaxf(acc.y * dv + b.y, 0.f);
    float4 wv = *(const float4*)&Weff[l2 * 2];
    float z0 = acc.x * wv.x + acc.y * wv.z;
    float z1 = acc.x * wv.y + acc.y * wv.w;
#pragma unroll
    for (int off = 32; off >= 1; off >>= 1) {
        z0 += __shfl_xor(z0, off, 64);
        z1 += __shfl_xor(z1, off, 64);
    }
    if (lane == 0) z[v] = make_float2(z0, z1);
}

// ---------------- fused layer-2 agg + mean-pool on projected z -----------
// per-wave private LDS accumulators (4x less same-address contention)

__global__ __launch_bounds__(256) void k_pool_edges(const float2* __restrict__ z,
                                                    const int* __restrict__ src,
                                                    const int* __restrict__ dst,
                                                    const float* __restrict__ dinv,
                                                    const int* __restrict__ batch,
                                                    float* __restrict__ tsum,
                                                    int* __restrict__ cnt,
                                                    int n, int E) {
    __shared__ float t[4][NGRAPH * 2];
    __shared__ int scnt[4][NGRAPH];
    int tid = threadIdx.x;
    int wv = tid >> 6;
    for (int j = tid; j < 4 * NGRAPH * 2; j += 256) ((float*)t)[j] = 0.f;
    for (int j = tid; j < 4 * NGRAPH; j += 256) ((int*)scnt)[j] = 0;
    __syncthreads();

    int i = (blockIdx.x * 256 + tid) * 4;
    int stride = POOLBLK * 256 * 4;
    for (; i < E; i += stride) {
        if (i + 3 < E) {
            int4 s4 = *(const int4*)&src[i];
            int4 d4 = *(const int4*)&dst[i];
            float w0 = dinv[s4.x] * dinv[d4.x];
            float w1 = dinv[s4.y] * dinv[d4.y];
            float w2 = dinv[s4.z] * dinv[d4.z];
            float w3 = dinv[s4.w] * dinv[d4.w];
            float2 z0 = z[s4.x], z1 = z[s4.y], z2 = z[s4.z], z3 = z[s4.w];
            int g0 = batch[d4.x], g1 = batch[d4.y], g2 = batch[d4.z], g3 = batch[d4.w];
            atomicAdd(&t[wv][g0 * 2],     w0 * z0.x);
            atomicAdd(&t[wv][g0 * 2 + 1], w0 * z0.y);
            atomicAdd(&t[wv][g1 * 2],     w1 * z1.x);
            atomicAdd(&t[wv][g1 * 2 + 1], w1 * z1.y);
            atomicAdd(&t[wv][g2 * 2],     w2 * z2.x);
            atomicAdd(&t[wv][g2 * 2 + 1], w2 * z2.y);
            atomicAdd(&t[wv][g3 * 2],     w3 * z3.x);
            atomicAdd(&t[wv][g3 * 2 + 1], w3 * z3.y);
        } else {
            for (int j = i; j < E; ++j) {
                int s = src[j], d = dst[j];
                float w = dinv[s] * dinv[d];
                float2 zv = z[s];
                int g = batch[d];
                atomicAdd(&t[wv][g * 2],     w * zv.x);
                atomicAdd(&t[wv][g * 2 + 1], w * zv.y);
            }
        }
    }
    for (int v = blockIdx.x * 256 + tid; v < n; v += POOLBLK * 256) {
        float dv = dinv[v];
        float2 zv = z[v];
        int g = batch[v];
        float w = dv * dv;
        atomicAdd(&t[wv][g * 2],     w * zv.x);
        atomicAdd(&t[wv][g * 2 + 1], w * zv.y);
        atomicAdd(&scnt[wv][g], 1);
    }
    __syncthreads();
    if (tid < NGRAPH * 2) {
        float s = t[0][tid] + t[1][tid] + t[2][tid] + t[3][tid];
        if (s != 0.f) atomicAdd(&tsum[tid], s);
    }
    if (tid < NGRAPH) {
        int s = scnt[0][tid] + scnt[1][tid] + scnt[2][tid] + scnt[3][tid];
        if (s) atomicAdd(&cnt[tid], s);
    }
}

__global__ void k_classify(const float* __restrict__ tsum, const int* __restrict__ cnt,
                           const float* __restrict__ beff, const float* __restrict__ bc,
                           float* __restrict__ out) {
    int t = threadIdx.x;
    if (t >= NGRAPH * 2) return;
    int g = t >> 1, c = t & 1;
    int cg = cnt[g];
    out[t] = cg ? (tsum[t] / (float)cg + beff[c]) : bc[c];
}

// ---------------- launch ----------------

extern "C" void kernel_launch(void* const* d_in, const int* in_sizes, int n_in,
                              void* d_out, int out_size, void* d_ws, size_t ws_size,
                              hipStream_t stream) {
    const float* x    = (const float*)d_in[0];
    const int*   ei   = (const int*)d_in[1];
    const int*   batch= (const int*)d_in[2];
    const float* W1   = (const float*)d_in[3];
    const float* b1   = (const float*)d_in[4];
    const float* W2   = (const float*)d_in[5];
    const float* b2   = (const float*)d_in[6];
    const float* Wc   = (const float*)d_in[7];
    const float* bc   = (const float*)d_in[8];

    const int n = in_sizes[0] / D;       // 100000
    const int E = in_sizes[1] / 2;       // 3200000
    const int* src = ei;
    const int* dst = ei + E;
    const int nb = (n + WINSZ - 1) / WINSZ;   // 391 dst-windows

    char* ws = (char*)d_ws;
    size_t off = 0;
    auto carve = [&](size_t bytes) -> char* {
        char* p = ws + off;
        off = (off + bytes + 255) & ~(size_t)255;
        return p;
    };
    unsigned short* bufBF = (unsigned short*)carve((size_t)n * D * 2);   // H' (bf16, dinv-scaled)
    float2* z     = (float2*)carve((size_t)n * 8);                       // projected h1
    unsigned* ebuf= (unsigned*)carve((size_t)nb * WINSLOTS * 4);         // windowed edges
    int*   csr    = (int*)  carve((size_t)nb * WINSLOTS * 4);            // windowed CSR
    // zero-region: cursor | tsum | cnt  (one memset)
    const int zero_words = 512 + NGRAPH * 2 + NGRAPH;
    int*   cursor = (int*)  carve(zero_words * 4);
    float* tsum   = (float*)(cursor + 512);
    int*   cnt    = (int*)  (tsum + NGRAPH * 2);
    int2*  offcnt = (int2*) carve((size_t)n * 8);
    float* dinv   = (float*)carve((size_t)n * 4);
    float* Weff   = (float*)carve(D * 2 * 4);
    float* beff   = (float*)carve(2 * 4);

    hipMemsetAsync(cursor, 0, zero_words * 4, stream);

    // CSR build (windowed counting sort); k_part block 0 also folds Weff/beff
    k_part<<<(E + PBCHUNK - 1) / PBCHUNK, 256, 0, stream>>>(src, dst, cursor, ebuf,
                                                            W2, Wc, b2, bc, Weff, beff, E, nb);
    k_csrwin<<<nb, 256, 0, stream>>>(ebuf, cursor, csr, offcnt, dinv, n);

    // layer 1 GEMM (MFMA bf16, direct-global A, in-kernel W1 conversion)
    k_gemm_mfma<<<(n + 63) / 64, 256, 0, stream>>>(x, W1, dinv, bufBF, n);
    // layer-1 agg (unweighted sum of pre-scaled rows) + relu + project to z
    k_agg_proj<<<(n + 3) / 4, 256, 0, stream>>>(bufBF, offcnt, csr, dinv, b1, Weff, z, n);

    // fused layer-2 agg + mean-pool on z (raw edge stream)
    k_pool_edges<<<POOLBLK, 256, 0, stream>>>(z, src, dst, dinv, batch, tsum, cnt, n, E);
    k_classify<<<1, 128, 0, stream>>>(tsum, cnt, beff, bc, (float*)d_out);
}